// Round 11
// baseline (224.481 us; speedup 1.0000x reference)
//
#include <hip/hip_runtime.h>

#define E_EDGES 800000
#define NN 50000
#define D_IN 96
#define D_EDGE 32
#define D_OUT 96
#define KSUM 512             // 4 types x 128 feat dims
#define SSTRIDE 520          // +8 bf16 pad (row 1040 B)
#define NB3 1564             // buckets of 32 nodes (dst>>5); 1564*32 = 50048
#define BCAP3 704            // bucket mean ~511.5, +8.5 sigma headroom
#define NCHUNK 256
#define CHE 3125             // edges per scat chunk (256*3125 = 800000)
#define CHIT 13              // ceil(3125/256)
#define BUILD_BLOCKS 512
#define SPT 7                // scan entries per thread: 256*7 >= NB3

typedef __attribute__((ext_vector_type(8))) __bf16 bf16x8;
typedef __attribute__((ext_vector_type(4))) float floatx4;

__device__ __forceinline__ float lo16(unsigned int u) {
    return __builtin_bit_cast(float, u << 16);
}
__device__ __forceinline__ float hi16(unsigned int u) {
    return __builtin_bit_cast(float, u & 0xFFFF0000u);
}
__device__ __forceinline__ unsigned int pk2(float a, float b) {
    unsigned short ua = __builtin_bit_cast(unsigned short, (__bf16)a);
    unsigned short ub = __builtin_bit_cast(unsigned short, (__bf16)b);
    return (unsigned int)ua | ((unsigned int)ub << 16);
}

// ---------- k_prep: blocks 0..255 = staged bucket scatter; 256..767 = tables --
// packed edge: (src<<6) bits 6..21 | ty bits 22..23 | dstLocal bits 24..28
__global__ __launch_bounds__(256) void k_prep(const int* __restrict__ ei,
                                              const int* __restrict__ et,
                                              const float* __restrict__ x,
                                              const float* __restrict__ ef,
                                              const float* __restrict__ Wm,
                                              int* __restrict__ cursor,
                                              int* __restrict__ eb,
                                              __bf16* __restrict__ WT,
                                              unsigned int* __restrict__ xeb) {
    __shared__ int lcnt[NB3];
    __shared__ int lexcl[NB3];
    __shared__ int gb[NB3];
    __shared__ int tmp[256];
    __shared__ int stage[CHE];
    __shared__ int spos[CHE];
    int tid = threadIdx.x, bid = blockIdx.x;

    if (bid < NCHUNK) {
        int e0 = bid * CHE;
        for (int i = tid; i < NB3; i += 256) lcnt[i] = 0;
        __syncthreads();

        int pv[CHIT], br[CHIT];
#pragma unroll
        for (int it = 0; it < CHIT; it++) {
            int i = it * 256 + tid;
            br[it] = -1;
            if (i < CHE) {
                int e = e0 + i;
                int dst = ei[E_EDGES + e];
                int b = dst >> 5;
                int rank = atomicAdd(&lcnt[b], 1);          // LDS atomic
                pv[it] = (ei[e] << 6) | (et[e] << 22) | ((dst & 31) << 24);
                br[it] = rank | (b << 16);
            }
        }
        __syncthreads();
        // hierarchical exclusive scan of lcnt[0..NB3)
        {
            int s = 0;
#pragma unroll
            for (int k = 0; k < SPT; k++) {
                int idx = tid * SPT + k;
                if (idx < NB3) { lexcl[idx] = s; s += lcnt[idx]; }
            }
            tmp[tid] = s; __syncthreads();
            for (int d = 1; d < 256; d <<= 1) {
                int t = (tid >= d) ? tmp[tid - d] : 0;
                __syncthreads();
                tmp[tid] += t; __syncthreads();
            }
            int base = tmp[tid] - s;       // exclusive thread base
#pragma unroll
            for (int k = 0; k < SPT; k++) {
                int idx = tid * SPT + k;
                if (idx < NB3) lexcl[idx] += base;
            }
        }
        for (int b = tid; b < NB3; b += 256)
            gb[b] = lcnt[b] ? atomicAdd(&cursor[b], lcnt[b]) : 0;
        __syncthreads();
        // stage edges bucket-sorted in LDS with their global positions
#pragma unroll
        for (int it = 0; it < CHIT; it++) {
            if (br[it] >= 0) {
                int b = br[it] >> 16, rank = br[it] & 0xFFFF;
                int lidx = lexcl[b] + rank;
                stage[lidx] = pv[it];
                int gp = gb[b] + rank;
                spos[lidx] = (gp < BCAP3) ? (b * BCAP3 + gp) : -1;
            }
        }
        __syncthreads();
        // coalesced-run write-out
        for (int i = tid; i < CHE; i += 256) {
            int p = spos[i];
            if (p >= 0) eb[p] = stage[i];
        }
    } else {
        // ---- xeb bf16 table + WT transpose ----
        int b2 = bid - NCHUNK;
        int gtid = b2 * 256 + tid;
        int lane = tid & 63, w = tid >> 6;
        for (int n = b2 * 4 + w; n < NN; n += BUILD_BLOCKS * 4) {
            float2 v;
            if (lane < 48) v = *(const float2*)(x  + (size_t)n * D_IN   + 2 * lane);
            else           v = *(const float2*)(ef + (size_t)n * D_EDGE + 2 * (lane - 48));
            xeb[(size_t)n * 64 + lane] = pk2(v.x, v.y);
        }
        for (int i = gtid; i < 96 * KSUM; i += BUILD_BLOCKS * 256) {
            int n = i >> 9, k = i & 511;
            WT[n * KSUM + k] = (__bf16)Wm[(size_t)k * 96 + n];
        }
    }
}

// ---------- k_fused: one 32-node bucket per block; read-once LDS sort ----------
// 256 threads = 4 waves. R11: ACCS is branch-free straight-line select-adds so
// the 8-gather batches stay fully in flight (R7-R10's per-edge branches
// serialized them -> 80 cyc/edge wall vs ~22 cyc of VALU).
__global__ __launch_bounds__(256, 6) void k_fused(const int* __restrict__ cursor,
                                               const int* __restrict__ eb,
                                               const unsigned int* __restrict__ xeb,
                                               const __bf16* __restrict__ WT,
                                               const float* __restrict__ bm,
                                               float* __restrict__ out) {
    __shared__ int ecopy[BCAP3];
    __shared__ int elist[BCAP3];
    __shared__ int h[128], hbase[128], c2[256];
    __shared__ __align__(16) __bf16 Sl[16][SSTRIDE];   // 16640 B; ~23.8 KB total

    int tid = threadIdx.x, lane = tid & 63, w = tid >> 6;
    int B = blockIdx.x;
    int seg = B * BCAP3;
    int m = min(cursor[B], BCAP3);

    if (tid < 128) h[tid] = 0;
    __syncthreads();

    // read bucket ONCE, histogram by key = (nodeLocal<<2)|ty
    for (int i = tid; i < m; i += 256) {
        int p = eb[seg + i];
        ecopy[i] = p;
        atomicAdd(&h[(p >> 22) & 127], 1);
    }
    __syncthreads();

    // 256-wide exclusive scan (keys padded with zeros above 128)
    int v = (tid < 128) ? h[tid] : 0;
    c2[tid] = v; __syncthreads();
    for (int d = 1; d < 256; d <<= 1) {
        int t = (tid >= d) ? c2[tid - d] : 0;
        __syncthreads();
        c2[tid] += t; __syncthreads();
    }
    if (tid < 128) { hbase[tid] = c2[tid] - v; }
    c2[tid] = c2[tid] - v;
    __syncthreads();

    // scatter into (node,type)-sorted elist
    for (int i = tid; i < m; i += 256) {
        int p = ecopy[i];
        int pos = atomicAdd(&c2[(p >> 22) & 127], 1);
        elist[pos] = p;
    }
    __syncthreads();

    unsigned int Mmask = (lane >= 48) ? 0x7FFFFFFFu : 0xFFFFFFFFu;

    // branch-free: ~20 straight-line VALU per edge, no scalar branches, no
    // readfirstlane -> compiler keeps all 8 gathers of a batch outstanding.
#define ACCS(u, v) do {                                                        \
        float f0 = lo16(u), f1 = hi16(u);                                      \
        f0 = __builtin_bit_cast(float,                                         \
                 __builtin_bit_cast(unsigned int, f0 - e0) & Mmask);           \
        f1 = __builtin_bit_cast(float,                                         \
                 __builtin_bit_cast(unsigned int, f1 - e1) & Mmask);           \
        int ty = ((v) >> 22) & 3;                                              \
        s0a += (ty == 0) ? f0 : 0.f;  s0b += (ty == 0) ? f1 : 0.f;             \
        s1a += (ty == 1) ? f0 : 0.f;  s1b += (ty == 1) ? f1 : 0.f;             \
        s2a += (ty == 2) ? f0 : 0.f;  s2b += (ty == 2) ? f1 : 0.f;             \
        s3a += (ty == 3) ? f0 : 0.f;  s3b += (ty == 3) ? f1 : 0.f;             \
    } while (0)

    int quad = lane >> 4, low = lane & 15;

    for (int ch = 0; ch < 2; ch++) {
        // ---- phase A: 16 nodes of this chunk ----
        for (int j = 0; j < 4; j++) {
            int lr = w * 4 + j;              // Sl row 0..15
            int nl = ch * 16 + lr;           // node-local 0..31
            int n = B * 32 + nl;
            int bs = hbase[nl * 4];
            int num = h[nl * 4] + h[nl * 4 + 1] + h[nl * 4 + 2] + h[nl * 4 + 3];
            float s0a = 0, s0b = 0, s1a = 0, s1b = 0,
                  s2a = 0, s2b = 0, s3a = 0, s3b = 0;
            float e0 = 0.f, e1 = 0.f;
            if (lane >= 48 && num > 0) {
                unsigned int u = xeb[(size_t)n * 64 + lane];   // dst's own ef pair
                e0 = lo16(u); e1 = hi16(u);
            }

            int i = 0;
            for (; i + 7 < num; i += 8) {                       // 8x MLP
                int v0 = elist[bs + i],     v1 = elist[bs + i + 1];
                int v2 = elist[bs + i + 2], v3 = elist[bs + i + 3];
                int v4 = elist[bs + i + 4], v5 = elist[bs + i + 5];
                int v6 = elist[bs + i + 6], v7 = elist[bs + i + 7];
                unsigned int u0 = xeb[(v0 & 0x3FFFFF) + lane];  // src*64 pre-shifted
                unsigned int u1 = xeb[(v1 & 0x3FFFFF) + lane];
                unsigned int u2 = xeb[(v2 & 0x3FFFFF) + lane];
                unsigned int u3 = xeb[(v3 & 0x3FFFFF) + lane];
                unsigned int u4 = xeb[(v4 & 0x3FFFFF) + lane];
                unsigned int u5 = xeb[(v5 & 0x3FFFFF) + lane];
                unsigned int u6 = xeb[(v6 & 0x3FFFFF) + lane];
                unsigned int u7 = xeb[(v7 & 0x3FFFFF) + lane];
                ACCS(u0, v0); ACCS(u1, v1); ACCS(u2, v2); ACCS(u3, v3);
                ACCS(u4, v4); ACCS(u5, v5); ACCS(u6, v6); ACCS(u7, v7);
            }
            for (; i + 3 < num; i += 4) {                       // 4x tail
                int v0 = elist[bs + i],     v1 = elist[bs + i + 1];
                int v2 = elist[bs + i + 2], v3 = elist[bs + i + 3];
                unsigned int u0 = xeb[(v0 & 0x3FFFFF) + lane];
                unsigned int u1 = xeb[(v1 & 0x3FFFFF) + lane];
                unsigned int u2 = xeb[(v2 & 0x3FFFFF) + lane];
                unsigned int u3 = xeb[(v3 & 0x3FFFFF) + lane];
                ACCS(u0, v0); ACCS(u1, v1); ACCS(u2, v2); ACCS(u3, v3);
            }
            for (; i < num; i++) {
                int vv = elist[bs + i];
                unsigned int u = xeb[(vv & 0x3FFFFF) + lane];
                ACCS(u, vv);
            }

            unsigned int* sp = (unsigned int*)&Sl[lr][0];
            sp[  0 + lane] = pk2(s0a, s0b);
            sp[ 64 + lane] = pk2(s1a, s1b);
            sp[128 + lane] = pk2(s2a, s2b);
            sp[192 + lane] = pk2(s3a, s3b);
        }
        __syncthreads();

        // ---- phase B: 16x96 = Sl[16x512] @ WT^T; 6 col tiles over 4 waves ----
        bf16x8 a[16];                       // A: m=low, k=ks*32+quad*8+j
        const __bf16* ap = &Sl[low][0] + quad * 8;
#pragma unroll
        for (int ks = 0; ks < 16; ks++) a[ks] = *(const bf16x8*)(ap + ks * 32);

        for (int ct = w; ct < 6; ct += 4) {
            floatx4 acc = {0.f, 0.f, 0.f, 0.f};
            const __bf16* bp = WT + (size_t)(ct * 16 + low) * KSUM + quad * 8;
#pragma unroll
            for (int ks = 0; ks < 16; ks++)
                acc = __builtin_amdgcn_mfma_f32_16x16x32_bf16(
                    a[ks], *(const bf16x8*)(bp + ks * 32), acc, 0, 0, 0);
            int col = ct * 16 + low;
#pragma unroll
            for (int rg = 0; rg < 4; rg++) {
                int r = quad * 4 + rg;              // C/D: row = quad*4+reg
                int nl = ch * 16 + r;
                int g = B * 32 + nl;
                if (g < NN) {
                    float bias = (float)h[nl * 4 + 0] * bm[col]
                               + (float)h[nl * 4 + 1] * bm[96 + col]
                               + (float)h[nl * 4 + 2] * bm[192 + col]
                               + (float)h[nl * 4 + 3] * bm[288 + col];
                    out[(size_t)g * D_OUT + col] = 0.25f * (acc[rg] + bias);
                }
            }
        }
        __syncthreads();   // before next chunk's phase A overwrites Sl
    }
#undef ACCS
}

extern "C" void kernel_launch(void* const* d_in, const int* in_sizes, int n_in,
                              void* d_out, int out_size, void* d_ws, size_t ws_size,
                              hipStream_t stream) {
    const float* x  = (const float*)d_in[0];
    const float* ef = (const float*)d_in[1];
    const int*   ei = (const int*)d_in[2];
    const int*   et = (const int*)d_in[3];
    const float* Wm = (const float*)d_in[4];
    const float* bm = (const float*)d_in[5];
    float* out = (float*)d_out;

    int* cursor = (int*)d_ws;                       // 2048 (NB3=1564 used)
    int* eb     = cursor + 2048;                    // NB3*BCAP3 (~4.4 MB)
    __bf16* WT  = (__bf16*)(eb + NB3 * BCAP3);      // 96*512 bf16
    unsigned int* xeb = (unsigned int*)(WT + 96 * KSUM);   // NN*64 dwords (~12.8 MB)
    // total ws ~17.4 MB

    hipMemsetAsync(cursor, 0, NB3 * sizeof(int), stream);
    k_prep <<<NCHUNK + BUILD_BLOCKS, 256, 0, stream>>>(ei, et, x, ef, Wm,
                                                       cursor, eb, WT, xeb);
    k_fused<<<NB3, 256, 0, stream>>>(cursor, eb, xeb, WT, bm, out);
}

// Round 12
// 184.870 us; speedup vs baseline: 1.2143x; 1.2143x over previous
//
#include <hip/hip_runtime.h>

#define E_EDGES 800000
#define NN 50000
#define D_IN 96
#define D_EDGE 32
#define D_OUT 96
#define KSUM 512             // 4 types x 128 feat dims
#define SSTRIDE 520          // +8 bf16 pad (row 1040 B)
#define NB4 3125             // buckets of 16 nodes (dst>>4); 3125*16 = 50000 exactly
#define BCAP4 384            // bucket mean 256, +8 sigma headroom
#define NCHUNK 256
#define CHE 3125             // edges per scat chunk (256*3125 = 800000)
#define CHIT 13              // ceil(3125/256)
#define BUILD_BLOCKS 512

typedef __attribute__((ext_vector_type(8))) __bf16 bf16x8;
typedef __attribute__((ext_vector_type(4))) float floatx4;

__device__ __forceinline__ float lo16(unsigned int u) {
    return __builtin_bit_cast(float, u << 16);
}
__device__ __forceinline__ float hi16(unsigned int u) {
    return __builtin_bit_cast(float, u & 0xFFFF0000u);
}
__device__ __forceinline__ unsigned int pk2(float a, float b) {
    unsigned short ua = __builtin_bit_cast(unsigned short, (__bf16)a);
    unsigned short ub = __builtin_bit_cast(unsigned short, (__bf16)b);
    return (unsigned int)ua | ((unsigned int)ub << 16);
}

// ---------- k_prep: blocks 0..255 = bucket scatter; 256..767 = tables ----------
// packed edge: (src<<6) bits 6..21 | ty bits 22..23 | dstLocal bits 24..27
// => (p>>22)&63 == (dstLocal<<2)|ty  (k_fused sort key, free)
__global__ __launch_bounds__(256) void k_prep(const int* __restrict__ ei,
                                              const int* __restrict__ et,
                                              const float* __restrict__ x,
                                              const float* __restrict__ ef,
                                              const float* __restrict__ Wm,
                                              int* __restrict__ cursor,
                                              int* __restrict__ eb,
                                              __bf16* __restrict__ WT,
                                              unsigned int* __restrict__ xeb) {
    __shared__ int lcnt[NB4];
    __shared__ int gb[NB4];
    int tid = threadIdx.x, bid = blockIdx.x;

    if (bid < NCHUNK) {
        int e0 = bid * CHE;
        for (int i = tid; i < NB4; i += 256) lcnt[i] = 0;
        __syncthreads();

        int pv[CHIT], br[CHIT];
#pragma unroll
        for (int it = 0; it < CHIT; it++) {
            int i = it * 256 + tid;
            br[it] = -1;
            if (i < CHE) {
                int e = e0 + i;
                int dst = ei[E_EDGES + e];
                int b = dst >> 4;
                int rank = atomicAdd(&lcnt[b], 1);          // LDS atomic
                pv[it] = (ei[e] << 6) | (et[e] << 22) | ((dst & 15) << 24);
                br[it] = rank | (b << 16);                  // rank < 2^16 always
            }
        }
        __syncthreads();
        for (int b = tid; b < NB4; b += 256)
            gb[b] = lcnt[b] ? atomicAdd(&cursor[b], lcnt[b]) : 0;
        __syncthreads();
#pragma unroll
        for (int it = 0; it < CHIT; it++) {
            if (br[it] >= 0) {
                int b = br[it] >> 16, rank = br[it] & 0xFFFF;
                int pos = gb[b] + rank;
                if (pos < BCAP4) eb[b * BCAP4 + pos] = pv[it];
            }
        }
    } else {
        // ---- xeb bf16 table + WT transpose ----
        int b2 = bid - NCHUNK;
        int gtid = b2 * 256 + tid;
        int lane = tid & 63, w = tid >> 6;
        for (int n = b2 * 4 + w; n < NN; n += BUILD_BLOCKS * 4) {
            float2 v;
            if (lane < 48) v = *(const float2*)(x  + (size_t)n * D_IN   + 2 * lane);
            else           v = *(const float2*)(ef + (size_t)n * D_EDGE + 2 * (lane - 48));
            xeb[(size_t)n * 64 + lane] = pk2(v.x, v.y);
        }
        for (int i = gtid; i < 96 * KSUM; i += BUILD_BLOCKS * 256) {
            int n = i >> 9, k = i & 511;
            WT[n * KSUM + k] = (__bf16)Wm[(size_t)k * 96 + n];
        }
    }
}

// ---------- k_fused: one 16-node bucket per block ----------
// 256 threads = 4 waves; wave w owns nodes 4w..4w+3. Edges (node,type)-sorted
// in LDS, then phase A loops per-(node,type) SEGMENT: type is segment-uniform
// so only 2 accumulators are live -> low register pressure -> the compiler can
// keep whole 4-gather batches in flight (R10's 8-accum + type-dispatch form
// pinned MLP~=1 -> 80 cyc/edge wall). Batches padded to 4 w/ validity masks
// so there are no serial-latency single-edge tails.
__global__ __launch_bounds__(256) void k_fused(const int* __restrict__ cursor,
                                               const int* __restrict__ eb,
                                               const unsigned int* __restrict__ xeb,
                                               const __bf16* __restrict__ WT,
                                               const float* __restrict__ bm,
                                               float* __restrict__ out) {
    __shared__ int ecopy[BCAP4];
    __shared__ int elist[BCAP4];
    __shared__ int h[64], hbase[64];
    __shared__ int c2[64];
    __shared__ __align__(16) __bf16 Sl[16][SSTRIDE];   // 16640 B; ~20.5 KB total

    int tid = threadIdx.x, lane = tid & 63, w = tid >> 6;
    int B = blockIdx.x;
    int seg = B * BCAP4;
    int m = min(cursor[B], BCAP4);

    if (tid < 64) h[tid] = 0;
    __syncthreads();

    // read bucket once, histogram by key = (nodeLocal<<2)|ty
    for (int i = tid; i < m; i += 256) {
        int p = eb[seg + i];
        ecopy[i] = p;
        atomicAdd(&h[(p >> 22) & 63], 1);
    }
    __syncthreads();

    // 64-key exclusive scan: single wave, shuffle only, zero barriers inside
    if (w == 0) {
        int v = h[lane];
        int s = v;
        for (int d = 1; d < 64; d <<= 1) {
            int t = __shfl_up(s, d, 64);
            if (lane >= d) s += t;
        }
        hbase[lane] = s - v;
        c2[lane] = s - v;
    }
    __syncthreads();

    // scatter into (node,type)-sorted elist
    for (int i = tid; i < m; i += 256) {
        int p = ecopy[i];
        int pos = atomicAdd(&c2[(p >> 22) & 63], 1);
        elist[pos] = p;
    }
    __syncthreads();

    unsigned int Mmask = (lane >= 48) ? 0x7FFFFFFFu : 0xFFFFFFFFu;
    int quad = lane >> 4, low = lane & 15;

    // ---- phase A: per-node, per-type segments; 2 live accumulators ----
#define EDGE(k) do {                                                           \
        float f0 = lo16(u##k), f1 = hi16(u##k);                                \
        f0 = __builtin_bit_cast(float,                                         \
                 __builtin_bit_cast(unsigned int, f0 - e0) & Mmask);           \
        f1 = __builtin_bit_cast(float,                                         \
                 __builtin_bit_cast(unsigned int, f1 - e1) & Mmask);           \
        sa += (i + k < num) ? f0 : 0.f;                                        \
        sb += (i + k < num) ? f1 : 0.f;                                        \
    } while (0)

    for (int j = 0; j < 4; j++) {
        int nl = w * 4 + j;                  // node-local 0..15, Sl row
        int n = B * 16 + nl;                 // global node (< 50000 always)
        float e0 = 0.f, e1 = 0.f;
        if (lane >= 48) {
            unsigned int u = xeb[(size_t)n * 64 + lane];   // dst's own ef pair
            e0 = lo16(u); e1 = hi16(u);
        }
        unsigned int* sp = (unsigned int*)&Sl[nl][0];

#pragma unroll
        for (int t = 0; t < 4; t++) {
            int bs = hbase[nl * 4 + t];
            int num = h[nl * 4 + t];
            float sa = 0.f, sb = 0.f;
            for (int i = 0; i < num; i += 4) {             // padded 4-batches
                int i1 = bs + i + 1, i2 = bs + i + 2, i3 = bs + i + 3;
                int lim = m - 1;
                int v0 = elist[bs + i];
                int v1 = elist[i1 < m ? i1 : lim];
                int v2 = elist[i2 < m ? i2 : lim];
                int v3 = elist[i3 < m ? i3 : lim];
                unsigned int u0 = xeb[(v0 & 0x3FFFFF) + lane];  // src*64 pre-shifted
                unsigned int u1 = xeb[(v1 & 0x3FFFFF) + lane];
                unsigned int u2 = xeb[(v2 & 0x3FFFFF) + lane];
                unsigned int u3 = xeb[(v3 & 0x3FFFFF) + lane];
                EDGE(0); EDGE(1); EDGE(2); EDGE(3);
            }
            sp[t * 64 + lane] = pk2(sa, sb);
        }
    }
#undef EDGE
    __syncthreads();

    // ---- phase B: 16x96 = Sl[16x512] @ WT^T; 6 col tiles over 4 waves ----
    bf16x8 a[16];                       // A: m=low, k=ks*32+quad*8+j
    const __bf16* ap = &Sl[low][0] + quad * 8;
#pragma unroll
    for (int ks = 0; ks < 16; ks++) a[ks] = *(const bf16x8*)(ap + ks * 32);

    for (int ct = w; ct < 6; ct += 4) {
        floatx4 acc = {0.f, 0.f, 0.f, 0.f};
        const __bf16* bp = WT + (size_t)(ct * 16 + low) * KSUM + quad * 8;
#pragma unroll
        for (int ks = 0; ks < 16; ks++)
            acc = __builtin_amdgcn_mfma_f32_16x16x32_bf16(
                a[ks], *(const bf16x8*)(bp + ks * 32), acc, 0, 0, 0);
        int col = ct * 16 + low;
#pragma unroll
        for (int rg = 0; rg < 4; rg++) {
            int r = quad * 4 + rg;              // C/D: row = quad*4+reg
            int g = B * 16 + r;                 // < 50000 always (3125*16)
            float bias = (float)h[r * 4 + 0] * bm[col]
                       + (float)h[r * 4 + 1] * bm[96 + col]
                       + (float)h[r * 4 + 2] * bm[192 + col]
                       + (float)h[r * 4 + 3] * bm[288 + col];
            out[(size_t)g * D_OUT + col] = 0.25f * (acc[rg] + bias);
        }
    }
}

extern "C" void kernel_launch(void* const* d_in, const int* in_sizes, int n_in,
                              void* d_out, int out_size, void* d_ws, size_t ws_size,
                              hipStream_t stream) {
    const float* x  = (const float*)d_in[0];
    const float* ef = (const float*)d_in[1];
    const int*   ei = (const int*)d_in[2];
    const int*   et = (const int*)d_in[3];
    const float* Wm = (const float*)d_in[4];
    const float* bm = (const float*)d_in[5];
    float* out = (float*)d_out;

    int* cursor = (int*)d_ws;                       // 3200 (NB4=3125 used)
    int* eb     = cursor + 3200;                    // NB4*BCAP4 (~4.8 MB)
    __bf16* WT  = (__bf16*)(eb + NB4 * BCAP4);      // 96*512 bf16
    unsigned int* xeb = (unsigned int*)(WT + 96 * KSUM);   // NN*64 dwords (~12.8 MB)
    // total ws ~17.8 MB

    hipMemsetAsync(cursor, 0, NB4 * sizeof(int), stream);
    k_prep <<<NCHUNK + BUILD_BLOCKS, 256, 0, stream>>>(ei, et, x, ef, Wm,
                                                       cursor, eb, WT, xeb);
    k_fused<<<NB4, 256, 0, stream>>>(cursor, eb, xeb, WT, bm, out);
}